// Round 7
// baseline (178.428 us; speedup 1.0000x reference)
//
#include <hip/hip_runtime.h>
#include <hip/hip_bf16.h>

#define B_ 256
#define L_ 225
#define D_ 1280
#define H_ 256
#define U_ 256

typedef __bf16  bf16x8 __attribute__((ext_vector_type(8)));
typedef float   f32x4  __attribute__((ext_vector_type(4)));
typedef unsigned short u16x8 __attribute__((ext_vector_type(8)));

__device__ __forceinline__ unsigned short f2bf(float f) {
    union { __hip_bfloat16 h; unsigned short u; } cv;
    cv.h = __float2bfloat16(f);   // RNE
    return cv.u;
}

__device__ __forceinline__ bf16x8 cvt8(f32x4 lo, f32x4 hi) {
    union { u16x8 u; bf16x8 h; } cv;
    cv.u[0] = f2bf(lo[0]); cv.u[1] = f2bf(lo[1]); cv.u[2] = f2bf(lo[2]); cv.u[3] = f2bf(lo[3]);
    cv.u[4] = f2bf(hi[0]); cv.u[5] = f2bf(hi[1]); cv.u[6] = f2bf(hi[2]); cv.u[7] = f2bf(hi[3]);
    return cv.h;
}

__device__ __forceinline__ void gload_lds16(const void* g, void* l) {
    __builtin_amdgcn_global_load_lds(
        (const __attribute__((address_space(1))) unsigned int*)g,
        (__attribute__((address_space(3))) unsigned int*)l,
        16, 0, 0);
}

__device__ __forceinline__ float wredsum(float x) {
#pragma unroll
    for (int off = 32; off > 0; off >>= 1) x += __shfl_xor(x, off, 64);
    return x;
}

// ---------------- kernel 1: W1 [D][U] f32 -> W1t [U][D] bf16 ----------------
__global__ void k_prep_w1t(const float* __restrict__ W1, __hip_bfloat16* __restrict__ w1t) {
    int idx = blockIdx.x * 256 + threadIdx.x;   // idx = k*U_+u
    int k = idx / U_;
    int u = idx % U_;
    w1t[(size_t)u * D_ + k] = __float2bfloat16(W1[idx]);
}

// ------------- kernel 2: ph[b][u] = hidden[b].W2[:,u] + b1[u] + b2[u] -------
__global__ void k_proj_h(const float* __restrict__ hidden, const float* __restrict__ W2,
                         const float* __restrict__ b1, const float* __restrict__ b2,
                         float* __restrict__ ph) {
    __shared__ float sh[H_];
    int b = blockIdx.x;
    int u = threadIdx.x;
    sh[u] = hidden[b * H_ + u];
    __syncthreads();
    float acc = b1[u] + b2[u];
#pragma unroll 8
    for (int h = 0; h < H_; ++h) acc += sh[h] * W2[h * U_ + u];
    ph[b * U_ + u] = acc;
}

// ---------------- kernel 3: GEMM + tanh*V -> logits -------------------------
// grid 1024 (b = blk>>2, quarter q = blk&3) x 128 threads (2 waves x 32 rows).
// A: global f32 -> regs -> bf16 (never in LDS). B: W1t chunk [256u][64k] in
// LDS (32 KB, single-buffered, swizzled). 4 blocks/CU co-resident; their
// staggered compute hides each other's stage drains.
__global__ __launch_bounds__(128, 2) void k_gemm(
        const float* __restrict__ feat,
        const __hip_bfloat16* __restrict__ w1t,
        const float* __restrict__ ph,
        const float* __restrict__ Vv,
        float* __restrict__ logits) {
    __shared__ __align__(128) char sB[32768];

    const int tid  = threadIdx.x;
    const int lane = tid & 63;
    const int wave = tid >> 6;           // 0..1
    const int blk  = blockIdx.x;
    const int b    = blk >> 2;
    const int q    = blk & 3;
    const int rbase = q * 64 + wave * 32;    // first row of this wave's stripe
    const int koff  = (lane >> 4) << 3;      // 0,8,16,24 : k-offset within frag

    const float* featB = feat + (size_t)b * L_ * D_;
    int rowA[2];
#pragma unroll
    for (int mi = 0; mi < 2; ++mi) {
        int r = rbase + mi * 16 + (lane & 15);
        rowA[mi] = r < L_ ? r : (L_ - 1);
    }
    const float* aPtr[2];
#pragma unroll
    for (int mi = 0; mi < 2; ++mi)
        aPtr[mi] = featB + (size_t)rowA[mi] * D_ + koff;

    f32x4 acc[2][16];
#pragma unroll
    for (int mi = 0; mi < 2; ++mi)
#pragma unroll
        for (int ni = 0; ni < 16; ++ni)
            acc[mi][ni] = (f32x4){0.f, 0.f, 0.f, 0.f};

    for (int kt = 0; kt < 20; ++kt) {
        __syncthreads();   // previous chunk's compute done; sB writable
        // stage B chunk kt: linear LDS dest, inverse-swizzled global source
#pragma unroll
        for (int pass = 0; pass < 16; ++pass) {
            int sI  = pass * 128 + tid;          // 0..2047
            int u   = sI >> 3;
            int c8  = (sI & 7) ^ (u & 7);
            gload_lds16(w1t + (size_t)u * D_ + kt * 64 + c8 * 8, sB + sI * 16);
        }
        // A-frag loads for chunk kt (global -> regs), overlap with stage
        f32x4 af[4][2];
#pragma unroll
        for (int mi = 0; mi < 2; ++mi)
#pragma unroll
            for (int ks = 0; ks < 2; ++ks) {
                const float* p = aPtr[mi] + kt * 64 + ks * 32;
                af[mi * 2 + ks][0] = *reinterpret_cast<const f32x4*>(p);
                af[mi * 2 + ks][1] = *reinterpret_cast<const f32x4*>(p + 4);
            }
        bf16x8 a[2][2];
#pragma unroll
        for (int mi = 0; mi < 2; ++mi)
#pragma unroll
            for (int ks = 0; ks < 2; ++ks)
                a[mi][ks] = cvt8(af[mi * 2 + ks][0], af[mi * 2 + ks][1]);
        __syncthreads();   // sB chunk kt visible (compiler drains vmcnt)

#pragma unroll
        for (int ks = 0; ks < 2; ++ks) {
            const int kk2 = (ks * 32 + koff) * 2;   // byte offset within 128B row
#pragma unroll
            for (int ni = 0; ni < 16; ++ni) {
                int u = ni * 16 + (lane & 15);
                bf16x8 bb = *reinterpret_cast<const bf16x8*>(
                    sB + u * 128 + (kk2 ^ ((u & 7) << 4)));
                acc[0][ni] = __builtin_amdgcn_mfma_f32_16x16x32_bf16(
                    a[0][ks], bb, acc[0][ni], 0, 0, 0);
                acc[1][ni] = __builtin_amdgcn_mfma_f32_16x16x32_bf16(
                    a[1][ks], bb, acc[1][ni], 0, 0, 0);
            }
        }
    }

    // ---- epilogue: logit[row] = sum_u tanh(acc+ph[u]) * V[u] ----
    float phu[16], vu[16];
#pragma unroll
    for (int ni = 0; ni < 16; ++ni) {
        int u = ni * 16 + (lane & 15);
        phu[ni] = ph[b * U_ + u];
        vu[ni]  = Vv[u];
    }
#pragma unroll
    for (int mi = 0; mi < 2; ++mi) {
#pragma unroll
        for (int rg = 0; rg < 4; ++rg) {
            int row = rbase + mi * 16 + ((lane >> 4) << 2) + rg;
            float s = 0.f;
#pragma unroll
            for (int ni = 0; ni < 16; ++ni) {
                float x = acc[mi][ni][rg] + phu[ni];
                s += (1.f - 2.f / (__expf(2.f * x) + 1.f)) * vu[ni];
            }
            s += __shfl_xor(s, 1, 64);
            s += __shfl_xor(s, 2, 64);
            s += __shfl_xor(s, 4, 64);
            s += __shfl_xor(s, 8, 64);
            if ((lane & 15) == 0 && row < L_) logits[b * L_ + row] = s;
        }
    }
}

// ---------------- kernel 4: w = exp(logit) (no max), den = sum --------------
__global__ void k_weights(const float* __restrict__ logits,
                          float* __restrict__ attnw, float* __restrict__ den) {
    __shared__ float red[4];
    int b = blockIdx.x;
    int t = threadIdx.x;           // 0..255
    float w = 0.f;
    if (t < L_) {
        w = __expf(logits[b * L_ + t]);   // |logit| <= sum|V| ~ 13: f32-safe
        attnw[b * L_ + t] = w;
    }
    float s = wredsum(w);
    if ((t & 63) == 0) red[t >> 6] = s;
    __syncthreads();
    if (t == 0) den[b] = red[0] + red[1] + red[2] + red[3];
}

// ---------------- kernel 5: context halves (pure streamer) ------------------
// grid 512 (b = blk>>1, half h = blk&1) x 320 threads: thread t owns f32x4
// [t*4, t*4+4) of D; block streams its half-batch contiguously (578 KB).
__global__ __launch_bounds__(320) void k_ctx(const float* __restrict__ feat,
                                             const float* __restrict__ attnw,
                                             float* __restrict__ num) {
    int blk = blockIdx.x;
    int b   = blk >> 1;
    int h   = blk & 1;
    int l0  = h * 113;
    int nl  = h ? 112 : 113;
    const float* fB = feat + ((size_t)b * L_ + l0) * D_;
    const float* wB = attnw + b * L_ + l0;
    int t = threadIdx.x;
    f32x4 c = (f32x4){0.f, 0.f, 0.f, 0.f};
    int l = 0;
    for (; l + 4 <= nl; l += 4) {
        float w0 = wB[l], w1 = wB[l + 1], w2 = wB[l + 2], w3 = wB[l + 3];
        c += w0 * *reinterpret_cast<const f32x4*>(fB + (size_t)(l + 0) * D_ + t * 4);
        c += w1 * *reinterpret_cast<const f32x4*>(fB + (size_t)(l + 1) * D_ + t * 4);
        c += w2 * *reinterpret_cast<const f32x4*>(fB + (size_t)(l + 2) * D_ + t * 4);
        c += w3 * *reinterpret_cast<const f32x4*>(fB + (size_t)(l + 3) * D_ + t * 4);
    }
    for (; l < nl; ++l)
        c += wB[l] * *reinterpret_cast<const f32x4*>(fB + (size_t)l * D_ + t * 4);
    *reinterpret_cast<f32x4*>(num + (size_t)blk * D_ + t * 4) = c;
}

// ---------------- kernel 6: combine halves, divide ---------------------------
__global__ void k_out(const float* __restrict__ num, const float* __restrict__ den,
                      float* __restrict__ out) {
    int b = blockIdx.x;
    int t = threadIdx.x;   // 0..319
    f32x4 s = *reinterpret_cast<const f32x4*>(num + (size_t)(b * 2) * D_ + t * 4)
            + *reinterpret_cast<const f32x4*>(num + (size_t)(b * 2 + 1) * D_ + t * 4);
    s *= (1.f / den[b]);
    *reinterpret_cast<f32x4*>(out + (size_t)b * D_ + t * 4) = s;
}

extern "C" void kernel_launch(void* const* d_in, const int* in_sizes, int n_in,
                              void* d_out, int out_size, void* d_ws, size_t ws_size,
                              hipStream_t stream) {
    const float* feat   = (const float*)d_in[0];
    const float* hidden = (const float*)d_in[1];
    const float* W1     = (const float*)d_in[2];
    const float* b1     = (const float*)d_in[3];
    const float* W2     = (const float*)d_in[4];
    const float* b2     = (const float*)d_in[5];
    const float* Vv     = (const float*)d_in[6];
    // bV (d_in[7]) is a uniform logit shift -> softmax-invariant; skipped.

    char* ws = (char*)d_ws;
    __hip_bfloat16* w1t = (__hip_bfloat16*)(ws);     // 655360 B
    float* ph     = (float*)(ws + 655360);           // 262144 B
    float* logits = (float*)(ws + 917504);           // 230400 B
    float* attnw  = (float*)(ws + 1147904);          // 230400 B
    float* den    = (float*)(ws + 1378304);          // 1024 B
    float* num    = (float*)(ws + 1379328);          // 2621440 B
    float* out    = (float*)d_out;

    k_prep_w1t<<<(U_ * D_) / 256, 256, 0, stream>>>(W1, w1t);
    k_proj_h  <<<B_, U_, 0, stream>>>(hidden, W2, b1, b2, ph);
    k_gemm    <<<B_ * 4, 128, 0, stream>>>(feat, w1t, ph, Vv, logits);
    k_weights <<<B_, 256, 0, stream>>>(logits, attnw, den);
    k_ctx     <<<B_ * 2, 320, 0, stream>>>(feat, attnw, num);
    k_out     <<<B_, 320, 0, stream>>>(num, den, out);
}

// Round 8
// 166.543 us; speedup vs baseline: 1.0714x; 1.0714x over previous
//
#include <hip/hip_runtime.h>
#include <hip/hip_bf16.h>

#define B_ 256
#define L_ 225
#define D_ 1280
#define H_ 256
#define U_ 256
#define BM 128
#define BN 256
#define BK 64
#define NMT 450   // 57600 / BM exactly

typedef __bf16  bf16x8 __attribute__((ext_vector_type(8)));
typedef float   f32x4  __attribute__((ext_vector_type(4)));
typedef unsigned short u16x8 __attribute__((ext_vector_type(8)));

__device__ __forceinline__ unsigned short f2bf(float f) {
    union { __hip_bfloat16 h; unsigned short u; } cv;
    cv.h = __float2bfloat16(f);   // RNE
    return cv.u;
}

__device__ __forceinline__ void gload_lds16(const void* g, void* l) {
    __builtin_amdgcn_global_load_lds(
        (const __attribute__((address_space(1))) unsigned int*)g,
        (__attribute__((address_space(3))) unsigned int*)l,
        16, 0, 0);
}

__device__ __forceinline__ float wredsum(float x) {
#pragma unroll
    for (int off = 32; off > 0; off >>= 1) x += __shfl_xor(x, off, 64);
    return x;
}

// ---------------- kernel 1: W1 [D][U] f32 -> W1t [U][D] bf16 ----------------
__global__ void k_prep_w1t(const float* __restrict__ W1, __hip_bfloat16* __restrict__ w1t) {
    int idx = blockIdx.x * 256 + threadIdx.x;   // idx = k*U_+u
    int k = idx / U_;
    int u = idx % U_;
    w1t[(size_t)u * D_ + k] = __float2bfloat16(W1[idx]);
}

// ------------- kernel 2: ph[b][u] = hidden[b].W2[:,u] + b1[u] + b2[u] -------
__global__ void k_proj_h(const float* __restrict__ hidden, const float* __restrict__ W2,
                         const float* __restrict__ b1, const float* __restrict__ b2,
                         float* __restrict__ ph) {
    __shared__ float sh[H_];
    int b = blockIdx.x;
    int u = threadIdx.x;
    sh[u] = hidden[b * H_ + u];
    __syncthreads();
    float acc = b1[u] + b2[u];
#pragma unroll 8
    for (int h = 0; h < H_; ++h) acc += sh[h] * W2[h * U_ + u];
    ph[b * U_ + u] = acc;
}

// ---------------- kernel 3: m97-style GEMM + tanh*V -> logits ---------------
// 450 blocks x 256 thr (4 waves, 2x2). Tile 128(flat M)x256(U), BK=64,
// single-buffered LDS (A 16K reg-cvt f32->bf16, B 32K via global_load_lds),
// 2 blocks/CU for cross-block barrier overlap. Wave tile 64x128 = acc[4][8].
__global__ __launch_bounds__(256, 2) void k_gemm(
        const float* __restrict__ feat,
        const __hip_bfloat16* __restrict__ w1t,
        const float* __restrict__ ph,
        const float* __restrict__ Vv,
        float* __restrict__ logits) {
    __shared__ __align__(128) char sA[16384];    // [128 rows][128 B] swizzled
    __shared__ __align__(128) char sB[32768];    // [256 u][128 B] swizzled
    __shared__ float sLg[2][BM];

    const int tid  = threadIdx.x;
    const int lane = tid & 63;
    const int wave = tid >> 6;      // 0..3
    const int wr   = wave >> 1;     // rows [wr*64, +64)
    const int wc   = wave & 1;      // cols [wc*128, +128)
    const int m0   = blockIdx.x * BM;

    // A-stage map: thread -> (row = tid>>1, seg = tid&1 covering 32 f32)
    const int arow = tid >> 1;
    const int aseg = tid & 1;
    const float* aSrc0 = feat + (size_t)(m0 + arow) * D_ + aseg * 32;
    const int aswz = (arow & 7) << 4;
    char* const aDstBase = sA + arow * 128;

    f32x4 acc[4][8];
#pragma unroll
    for (int mi = 0; mi < 4; ++mi)
#pragma unroll
        for (int ni = 0; ni < 8; ++ni)
            acc[mi][ni] = (f32x4){0.f, 0.f, 0.f, 0.f};

    for (int kt = 0; kt < 20; ++kt) {
        __syncthreads();   // previous compute done; buffers writable

        // B: 8 chunks/thread via global_load_lds (linear dest, pre-swz source)
#pragma unroll
        for (int p = 0; p < 8; ++p) {
            int sI = p * 256 + tid;            // 0..2047
            int u  = sI >> 3;
            int c8 = (sI & 7) ^ (u & 7);
            gload_lds16(w1t + (size_t)u * D_ + kt * 64 + c8 * 8, sB + sI * 16);
        }
        // A: 32 f32 -> 32 bf16, swizzled store
        {
            const float* src = aSrc0 + kt * 64;
            f32x4 v[8];
#pragma unroll
            for (int j = 0; j < 8; ++j) v[j] = *reinterpret_cast<const f32x4*>(src + j * 4);
#pragma unroll
            for (int j = 0; j < 4; ++j) {
                u16x8 w;
                w[0] = f2bf(v[2*j][0]);   w[1] = f2bf(v[2*j][1]);
                w[2] = f2bf(v[2*j][2]);   w[3] = f2bf(v[2*j][3]);
                w[4] = f2bf(v[2*j+1][0]); w[5] = f2bf(v[2*j+1][1]);
                w[6] = f2bf(v[2*j+1][2]); w[7] = f2bf(v[2*j+1][3]);
                *reinterpret_cast<u16x8*>(aDstBase + ((aseg * 64 + j * 16) ^ aswz)) = w;
            }
        }
        __syncthreads();   // staged tile visible

        // compute: 2 k-slices of 32, 32 MFMA each
#pragma unroll
        for (int ks = 0; ks < 2; ++ks) {
            const int kk2 = (ks * 32 + ((lane >> 4) << 3)) * 2;
            bf16x8 a[4];
#pragma unroll
            for (int mi = 0; mi < 4; ++mi) {
                int r = wr * 64 + mi * 16 + (lane & 15);
                a[mi] = *reinterpret_cast<const bf16x8*>(sA + r * 128 + (kk2 ^ ((r & 7) << 4)));
            }
#pragma unroll
            for (int ni = 0; ni < 8; ++ni) {
                int u = wc * 128 + ni * 16 + (lane & 15);
                bf16x8 bb = *reinterpret_cast<const bf16x8*>(sB + u * 128 + (kk2 ^ ((u & 7) << 4)));
#pragma unroll
                for (int mi = 0; mi < 4; ++mi)
                    acc[mi][ni] = __builtin_amdgcn_mfma_f32_16x16x32_bf16(
                        a[mi], bb, acc[mi][ni], 0, 0, 0);
            }
        }
    }
    __syncthreads();   // last LDS reads done before sLg writes (aliasing-safe)

    // ---- epilogue: logit[m] = sum_u tanh(acc + ph[b(m)][u]) * V[u] ----
    const int bb0 = m0 / L_;
    const int rb  = (bb0 + 1) * L_ - m0;          // rows >= rb are batch bb0+1
    const int b1  = bb0 + 1 <= 255 ? bb0 + 1 : 255;
    float phA[8], phB[8], vu[8];
#pragma unroll
    for (int ni = 0; ni < 8; ++ni) {
        int u = wc * 128 + ni * 16 + (lane & 15);
        phA[ni] = ph[bb0 * U_ + u];
        phB[ni] = ph[b1 * U_ + u];
        vu[ni]  = Vv[u];
    }
#pragma unroll
    for (int mi = 0; mi < 4; ++mi) {
#pragma unroll
        for (int rg = 0; rg < 4; ++rg) {
            int rloc = wr * 64 + mi * 16 + ((lane >> 4) << 2) + rg;
            bool hi = rloc >= rb;
            float s = 0.f;
#pragma unroll
            for (int ni = 0; ni < 8; ++ni) {
                float x = acc[mi][ni][rg] + (hi ? phB[ni] : phA[ni]);
                s += (1.f - 2.f / (__expf(2.f * x) + 1.f)) * vu[ni];
            }
            s += __shfl_xor(s, 1, 64);
            s += __shfl_xor(s, 2, 64);
            s += __shfl_xor(s, 4, 64);
            s += __shfl_xor(s, 8, 64);
            if ((lane & 15) == 0) sLg[wc][rloc] = s;
        }
    }
    __syncthreads();
    if (tid < BM) logits[m0 + tid] = sLg[0][tid] + sLg[1][tid];
}

// ---------------- kernel 4: w = exp(logit) (no max), den = sum --------------
__global__ void k_weights(const float* __restrict__ logits,
                          float* __restrict__ attnw, float* __restrict__ den) {
    __shared__ float red[4];
    int b = blockIdx.x;
    int t = threadIdx.x;           // 0..255
    float w = 0.f;
    if (t < L_) {
        w = __expf(logits[b * L_ + t]);   // |logit| <= sum|V| ~ 13: f32-safe
        attnw[b * L_ + t] = w;
    }
    float s = wredsum(w);
    if ((t & 63) == 0) red[t >> 6] = s;
    __syncthreads();
    if (t == 0) den[b] = red[0] + red[1] + red[2] + red[3];
}

// ---------------- kernel 5: context halves (pure streamer) ------------------
__global__ __launch_bounds__(320) void k_ctx(const float* __restrict__ feat,
                                             const float* __restrict__ attnw,
                                             float* __restrict__ num) {
    int blk = blockIdx.x;
    int b   = blk >> 1;
    int h   = blk & 1;
    int l0  = h * 113;
    int nl  = h ? 112 : 113;
    const float* fB = feat + ((size_t)b * L_ + l0) * D_;
    const float* wB = attnw + b * L_ + l0;
    int t = threadIdx.x;
    f32x4 c = (f32x4){0.f, 0.f, 0.f, 0.f};
    int l = 0;
    for (; l + 4 <= nl; l += 4) {
        float w0 = wB[l], w1 = wB[l + 1], w2 = wB[l + 2], w3 = wB[l + 3];
        c += w0 * *reinterpret_cast<const f32x4*>(fB + (size_t)(l + 0) * D_ + t * 4);
        c += w1 * *reinterpret_cast<const f32x4*>(fB + (size_t)(l + 1) * D_ + t * 4);
        c += w2 * *reinterpret_cast<const f32x4*>(fB + (size_t)(l + 2) * D_ + t * 4);
        c += w3 * *reinterpret_cast<const f32x4*>(fB + (size_t)(l + 3) * D_ + t * 4);
    }
    for (; l < nl; ++l)
        c += wB[l] * *reinterpret_cast<const f32x4*>(fB + (size_t)l * D_ + t * 4);
    *reinterpret_cast<f32x4*>(num + (size_t)blk * D_ + t * 4) = c;
}

// ---------------- kernel 6: combine halves, divide ---------------------------
__global__ void k_out(const float* __restrict__ num, const float* __restrict__ den,
                      float* __restrict__ out) {
    int b = blockIdx.x;
    int t = threadIdx.x;   // 0..319
    f32x4 s = *reinterpret_cast<const f32x4*>(num + (size_t)(b * 2) * D_ + t * 4)
            + *reinterpret_cast<const f32x4*>(num + (size_t)(b * 2 + 1) * D_ + t * 4);
    s *= (1.f / den[b]);
    *reinterpret_cast<f32x4*>(out + (size_t)b * D_ + t * 4) = s;
}

extern "C" void kernel_launch(void* const* d_in, const int* in_sizes, int n_in,
                              void* d_out, int out_size, void* d_ws, size_t ws_size,
                              hipStream_t stream) {
    const float* feat   = (const float*)d_in[0];
    const float* hidden = (const float*)d_in[1];
    const float* W1     = (const float*)d_in[2];
    const float* b1     = (const float*)d_in[3];
    const float* W2     = (const float*)d_in[4];
    const float* b2     = (const float*)d_in[5];
    const float* Vv     = (const float*)d_in[6];
    // bV (d_in[7]) is a uniform logit shift -> softmax-invariant; skipped.

    char* ws = (char*)d_ws;
    __hip_bfloat16* w1t = (__hip_bfloat16*)(ws);     // 655360 B
    float* ph     = (float*)(ws + 655360);           // 262144 B
    float* logits = (float*)(ws + 917504);           // 230400 B
    float* attnw  = (float*)(ws + 1147904);          // 230400 B
    float* den    = (float*)(ws + 1378304);          // 1024 B
    float* num    = (float*)(ws + 1379328);          // 2621440 B
    float* out    = (float*)d_out;

    k_prep_w1t<<<(U_ * D_) / 256, 256, 0, stream>>>(W1, w1t);
    k_proj_h  <<<B_, U_, 0, stream>>>(hidden, W2, b1, b2, ph);
    k_gemm    <<<NMT, 256, 0, stream>>>(feat, w1t, ph, Vv, logits);
    k_weights <<<B_, 256, 0, stream>>>(logits, attnw, den);
    k_ctx     <<<B_ * 2, 320, 0, stream>>>(feat, attnw, num);
    k_out     <<<B_, 320, 0, stream>>>(num, den, out);
}

// Round 9
// 127.474 us; speedup vs baseline: 1.3997x; 1.3065x over previous
//
#include <hip/hip_runtime.h>
#include <hip/hip_bf16.h>

#define B_ 256
#define L_ 225
#define D_ 1280
#define H_ 256
#define U_ 256

typedef __bf16  bf16x8 __attribute__((ext_vector_type(8)));
typedef float   f32x4  __attribute__((ext_vector_type(4)));
typedef unsigned short u16x8 __attribute__((ext_vector_type(8)));

__device__ __forceinline__ unsigned short f2bf(float f) {
    union { __hip_bfloat16 h; unsigned short u; } cv;
    cv.h = __float2bfloat16(f);   // RNE
    return cv.u;
}

__device__ __forceinline__ void gload_lds16(const void* g, void* l) {
    __builtin_amdgcn_global_load_lds(
        (const __attribute__((address_space(1))) unsigned int*)g,
        (__attribute__((address_space(3))) unsigned int*)l,
        16, 0, 0);
}

__device__ __forceinline__ float wredsum(float x) {
#pragma unroll
    for (int off = 32; off > 0; off >>= 1) x += __shfl_xor(x, off, 64);
    return x;
}

// ------ kernel 1: merged prep: W1t bf16 transpose + ph = hidden.W2+b1+b2 ----
__global__ void k_prep(const float* __restrict__ W1,
                       const float* __restrict__ hidden,
                       const float* __restrict__ W2,
                       const float* __restrict__ b1,
                       const float* __restrict__ b2,
                       __hip_bfloat16* __restrict__ w1t,
                       float* __restrict__ ph) {
    int bid = blockIdx.x;
    if (bid < 1280) {
        int idx = bid * 256 + threadIdx.x;   // idx = k*U_+u
        int k = idx / U_;
        int u = idx % U_;
        w1t[(size_t)u * D_ + k] = __float2bfloat16(W1[idx]);
    } else {
        __shared__ float sh[H_];
        int b = bid - 1280;
        int u = threadIdx.x;
        sh[u] = hidden[b * H_ + u];
        __syncthreads();
        float acc = b1[u] + b2[u];
#pragma unroll 8
        for (int h = 0; h < H_; ++h) acc += sh[h] * W2[h * U_ + u];
        ph[b * U_ + u] = acc;
    }
}

// ---------------- kernel 2: fully fused per-batch kernel --------------------
// 256 blocks (1/CU) x 1024 threads. Block b: GEMM(225pad256 x 256 x 1280) ->
// tanh*V -> exp weights (no-max) -> context (f32 re-read). T14 split staging.
// LDS: dbuf 2 x 65536 (A 32K swz + B 32K swz) | sV @131072 | sPh @132096
//      sL[4][256] @133120 | sW[256] @137216 | sRed[16] @138240
__global__ __launch_bounds__(1024, 4) void k_fused(
        const float* __restrict__ feat,
        const __hip_bfloat16* __restrict__ w1t,
        const float* __restrict__ ph,
        const float* __restrict__ Vv,
        float* __restrict__ out) {
    __shared__ __align__(128) char smem[138304];
    float* sV   = (float*)(smem + 131072);
    float* sPh  = (float*)(smem + 132096);
    float* sL   = (float*)(smem + 133120);
    float* sW   = (float*)(smem + 137216);
    float* sRed = (float*)(smem + 138240);

    const int tid  = threadIdx.x;
    const int lane = tid & 63;
    const int wave = tid >> 6;     // 0..15
    const int wr   = wave >> 2;    // rows [wr*64, +64)
    const int wc   = wave & 3;     // cols [wc*64, +64)
    const int b    = blockIdx.x;

    if (tid < 256) { sV[tid] = Vv[tid]; sPh[tid] = ph[b * 256 + tid]; }

    // A staging map: thread -> (row ar, 16-float k-chunk)
    const int ar    = tid >> 2;                  // 0..255
    const int arc   = ar < L_ ? ar : (L_ - 1);   // clamp padded rows
    const int akseg = (tid & 3) << 4;            // 0,16,32,48
    const float* aSrc0 = feat + ((size_t)(b * L_ + arc) * D_ + akseg);
    const int ac80 = akseg >> 3;
    const int aswz = (ar & 7) << 4;

    f32x4 acc[4][4];
#pragma unroll
    for (int mi = 0; mi < 4; ++mi)
#pragma unroll
        for (int ni = 0; ni < 4; ++ni)
            acc[mi][ni] = (f32x4){0.f, 0.f, 0.f, 0.f};

    auto loadA = [&](int kt, f32x4* v) {
        const float* src = aSrc0 + kt * 64;
        v[0] = *reinterpret_cast<const f32x4*>(src);
        v[1] = *reinterpret_cast<const f32x4*>(src + 4);
        v[2] = *reinterpret_cast<const f32x4*>(src + 8);
        v[3] = *reinterpret_cast<const f32x4*>(src + 12);
    };
    auto stageB = [&](int kt, char* bufB) {
#pragma unroll
        for (int pass = 0; pass < 2; ++pass) {
            int s   = pass * 1024 + tid;
            int u   = s >> 3;
            int c8s = s & 7;
            int c8g = c8s ^ (u & 7);
            gload_lds16(w1t + (size_t)u * D_ + kt * 64 + c8g * 8, bufB + s * 16);
        }
    };
    auto storeA = [&](const f32x4* v, char* bufA) {
        u16x8 w0, w1;
        w0[0] = f2bf(v[0][0]); w0[1] = f2bf(v[0][1]); w0[2] = f2bf(v[0][2]); w0[3] = f2bf(v[0][3]);
        w0[4] = f2bf(v[1][0]); w0[5] = f2bf(v[1][1]); w0[6] = f2bf(v[1][2]); w0[7] = f2bf(v[1][3]);
        w1[0] = f2bf(v[2][0]); w1[1] = f2bf(v[2][1]); w1[2] = f2bf(v[2][2]); w1[3] = f2bf(v[2][3]);
        w1[4] = f2bf(v[3][0]); w1[5] = f2bf(v[3][1]); w1[6] = f2bf(v[3][2]); w1[7] = f2bf(v[3][3]);
        *reinterpret_cast<u16x8*>(bufA + (ar << 7) + ((ac80 << 4) ^ aswz))       = w0;
        *reinterpret_cast<u16x8*>(bufA + (ar << 7) + (((ac80 + 1) << 4) ^ aswz)) = w1;
    };
    auto compute = [&](const char* bufA, const char* bufB) {
#pragma unroll
        for (int ks = 0; ks < 2; ++ks) {
            const int kk2 = (ks * 32 + ((lane >> 4) << 3)) * 2;
            bf16x8 a[4], bb[4];
#pragma unroll
            for (int mi = 0; mi < 4; ++mi) {
                int r = wr * 64 + mi * 16 + (lane & 15);
                a[mi] = *reinterpret_cast<const bf16x8*>(bufA + (r << 7) + (kk2 ^ ((r & 7) << 4)));
            }
#pragma unroll
            for (int ni = 0; ni < 4; ++ni) {
                int u = wc * 64 + ni * 16 + (lane & 15);
                bb[ni] = *reinterpret_cast<const bf16x8*>(bufB + (u << 7) + (kk2 ^ ((u & 7) << 4)));
            }
#pragma unroll
            for (int mi = 0; mi < 4; ++mi)
#pragma unroll
                for (int ni = 0; ni < 4; ++ni)
                    acc[mi][ni] = __builtin_amdgcn_mfma_f32_16x16x32_bf16(
                        a[mi], bb[ni], acc[mi][ni], 0, 0, 0);
        }
    };

    // ---- phase 1: K-streamed GEMM, dbuf, T14 split (load early, write late)
    {
        f32x4 v[4];
        loadA(0, v);
        stageB(0, smem + 32768);
        storeA(v, smem);
    }
    __syncthreads();
    int cur = 0;
    for (int kt = 0; kt < 20; ++kt) {
        char* bufN = smem + (cur ^ 1) * 65536;
        f32x4 v[4];
        if (kt < 19) { loadA(kt + 1, v); stageB(kt + 1, bufN + 32768); }
        char* bufC = smem + cur * 65536;
        compute(bufC, bufC + 32768);
        if (kt < 19) storeA(v, bufN);
        __syncthreads();
        cur ^= 1;
    }

    // ---- epilogue: tanh(acc+ph)*V -> logits; w = exp(logit) (no max) ----
    float phu[4], vu[4];
#pragma unroll
    for (int ni = 0; ni < 4; ++ni) {
        int u = wc * 64 + ni * 16 + (lane & 15);
        phu[ni] = sPh[u];
        vu[ni]  = sV[u];
    }
#pragma unroll
    for (int mi = 0; mi < 4; ++mi) {
#pragma unroll
        for (int rg = 0; rg < 4; ++rg) {
            int row = wr * 64 + mi * 16 + ((lane >> 4) << 2) + rg;
            float s = 0.f;
#pragma unroll
            for (int ni = 0; ni < 4; ++ni) {
                float x = acc[mi][ni][rg] + phu[ni];
                s += (1.f - 2.f / (__expf(2.f * x) + 1.f)) * vu[ni];
            }
            s += __shfl_xor(s, 1, 64);
            s += __shfl_xor(s, 2, 64);
            s += __shfl_xor(s, 4, 64);
            s += __shfl_xor(s, 8, 64);
            if ((lane & 15) == 0) sL[wc * 256 + row] = s;
        }
    }
    __syncthreads();
    float den_p = 0.f;
    if (tid < 256) {
        float lg = sL[tid] + sL[256 + tid] + sL[512 + tid] + sL[768 + tid];
        float w  = (tid < L_) ? __expf(lg) : 0.f;   // |lg| <= sum|V| ~ 13: safe
        sW[tid] = w;
        den_p = w;
    }
    den_p = wredsum(den_p);
    if (lane == 0) sRed[wave] = den_p;
    __syncthreads();

    // ---- phase 3: context = sum_l w_l * feat[b,l,:] (f32 re-read) ----
    f32x4 c[5];
#pragma unroll
    for (int ch = 0; ch < 5; ++ch) c[ch] = (f32x4){0.f, 0.f, 0.f, 0.f};
    {
        const float* fB = feat + (size_t)b * L_ * D_;
        int l = wave;
        for (; l + 16 < L_; l += 32) {
            float wa = sW[l], wb = sW[l + 16];
            const float* ra = fB + (size_t)l * D_ + (lane << 2);
            const float* rb = fB + (size_t)(l + 16) * D_ + (lane << 2);
#pragma unroll
            for (int ch = 0; ch < 5; ++ch) {
                c[ch] += wa * *reinterpret_cast<const f32x4*>(ra + ch * 256);
                c[ch] += wb * *reinterpret_cast<const f32x4*>(rb + ch * 256);
            }
        }
        if (l < L_) {
            float wa = sW[l];
            const float* ra = fB + (size_t)l * D_ + (lane << 2);
#pragma unroll
            for (int ch = 0; ch < 5; ++ch)
                c[ch] += wa * *reinterpret_cast<const f32x4*>(ra + ch * 256);
        }
    }

    // ---- final: reduce 16 wave partials, divide by den, write out ----
    float* pc = (float*)smem;   // [16][1280] f32, reuses dbuf region
#pragma unroll
    for (int ch = 0; ch < 5; ++ch)
        *reinterpret_cast<f32x4*>(pc + wave * 1280 + ch * 256 + (lane << 2)) = c[ch];
    __syncthreads();
    if (tid < 320) {
        f32x4 s = (f32x4){0.f, 0.f, 0.f, 0.f};
#pragma unroll
        for (int w = 0; w < 16; ++w)
            s += *reinterpret_cast<const f32x4*>(pc + w * 1280 + (tid << 2));
        float den = 0.f;
#pragma unroll
        for (int i = 0; i < 16; ++i) den += sRed[i];
        s *= (1.f / den);
        *reinterpret_cast<f32x4*>(out + (size_t)b * D_ + (tid << 2)) = s;
    }
}

extern "C" void kernel_launch(void* const* d_in, const int* in_sizes, int n_in,
                              void* d_out, int out_size, void* d_ws, size_t ws_size,
                              hipStream_t stream) {
    const float* feat   = (const float*)d_in[0];
    const float* hidden = (const float*)d_in[1];
    const float* W1     = (const float*)d_in[2];
    const float* b1     = (const float*)d_in[3];
    const float* W2     = (const float*)d_in[4];
    const float* b2     = (const float*)d_in[5];
    const float* Vv     = (const float*)d_in[6];
    // bV (d_in[7]) is a uniform logit shift -> softmax-invariant; skipped.

    char* ws = (char*)d_ws;
    __hip_bfloat16* w1t = (__hip_bfloat16*)(ws);        // 655360 B
    float* ph = (float*)(ws + 655360);                  // 262144 B
    float* out = (float*)d_out;

    k_prep <<<1536, 256, 0, stream>>>(W1, hidden, W2, b1, b2, w1t, ph);
    k_fused<<<B_, 1024, 0, stream>>>(feat, w1t, ph, Vv, out);
}